// Round 2
// baseline (518.657 us; speedup 1.0000x reference)
//
#include <hip/hip_runtime.h>

typedef unsigned int uint;
typedef unsigned short ushort;
typedef __bf16 bf16x8 __attribute__((ext_vector_type(8)));
typedef float f32x4 __attribute__((ext_vector_type(4)));
typedef uint u32x4 __attribute__((ext_vector_type(4)));

#define DEV static __device__ __forceinline__

// Problem constants
#define BATCH 2
#define SEQ 2048
#define DMODEL 2048
#define NHEADS 16
#define DHEAD 128
#define MROWS (BATCH*SEQ)          // 4096
#define RSCALE 0.08838834764831845f // 1/sqrt(128)

DEV bf16x8 as_frag(u32x4 v) { return __builtin_bit_cast(bf16x8, v); }
DEV ushort f2bf(float f) {
  uint u = __builtin_bit_cast(uint, f);
  u += 0x7fffu + ((u >> 16) & 1u);   // RNE
  return (ushort)(u >> 16);
}

// ---------------------------------------------------------------------------
// Flat fp32 -> bf16 conversion (x). n must be divisible by 4.
// ---------------------------------------------------------------------------
__global__ __launch_bounds__(256) void convert_f32_bf16(
    const float* __restrict__ src, ushort* __restrict__ dst, int n4)
{
  int i = blockIdx.x * 256 + threadIdx.x;
  if (i >= n4) return;
  const float4* s4 = (const float4*)src;
  float4 v = s4[i];
  union { ushort u[4]; uint2 w; } o;
  o.u[0] = f2bf(v.x); o.u[1] = f2bf(v.y); o.u[2] = f2bf(v.z); o.u[3] = f2bf(v.w);
  ((uint2*)dst)[i] = o.w;
}

// ---------------------------------------------------------------------------
// fp32 2D transpose + convert to bf16: src[slice][R][C] f32 -> dst[slice][C][R] bf16
// ---------------------------------------------------------------------------
__global__ __launch_bounds__(256) void transpose_f32_bf16(
    const float* __restrict__ src, ushort* __restrict__ dst, int R, int C)
{
  __shared__ ushort t[32][33];
  size_t slice = (size_t)blockIdx.z * R * C;
  src += slice; dst += slice;
  int c0 = blockIdx.x * 32, r0 = blockIdx.y * 32;
  int x = threadIdx.x & 31, y = threadIdx.x >> 5;   // 32 x 8
  #pragma unroll
  for (int i = 0; i < 32; i += 8) {
    t[y + i][x] = f2bf(src[(size_t)(r0 + y + i) * C + (c0 + x)]);
  }
  __syncthreads();
  #pragma unroll
  for (int i = 0; i < 32; i += 8) {
    dst[(size_t)(c0 + y + i) * R + (r0 + x)] = t[x][y + i];
  }
}

// ---------------------------------------------------------------------------
// QKV projection GEMM: C[128 pos][128 e] per (mtile, head, which)
// A = xb [4096][2048] bf16, Bt = W^T per head [128 e][2048 d] bf16
// Q/K out: [bh][pos][e]; V out written TRANSPOSED: Vt[bh][e][pos]
// ---------------------------------------------------------------------------
__global__ __launch_bounds__(256, 2) void gemm_qkv(
    const ushort* __restrict__ xb,
    const ushort* __restrict__ WqT, const ushort* __restrict__ WkT,
    const ushort* __restrict__ WvT,
    const float* __restrict__ bQ, const float* __restrict__ bK,
    const float* __restrict__ bV,
    ushort* __restrict__ Qo, ushort* __restrict__ Ko, ushort* __restrict__ Vt)
{
  int mt = blockIdx.x;       // 0..31
  int h  = blockIdx.y;       // 0..15
  int which = blockIdx.z;    // 0:Q 1:K 2:V
  const ushort* Bt = (which == 0) ? WqT : (which == 1) ? WkT : WvT;
  const float* bias = (which == 0) ? bQ : (which == 1) ? bK : bV;
  Bt += (size_t)h * DHEAD * DMODEL;
  bias += h * DHEAD;

  __shared__ u32x4 As[128 * 9];
  __shared__ u32x4 Bs[128 * 9];

  int tid = threadIdx.x;
  int lane = tid & 63, wid = tid >> 6;
  int wm = wid >> 1, wn = wid & 1;
  int l16 = lane & 15, quad = lane >> 4;

  const u32x4* Ag = (const u32x4*)xb + (size_t)(mt * 128) * 256;  // 2048 bf16 = 256 u32x4/row
  const u32x4* Bg = (const u32x4*)Bt;                             // [128][256]

  f32x4 acc[4][4] = {};

  for (int k0 = 0; k0 < DMODEL; k0 += 64) {
    int kv = k0 >> 3;
    #pragma unroll
    for (int i = 0; i < 4; i++) {
      int v = tid + i * 256;
      int row = v >> 3, c8 = v & 7;
      As[row * 9 + c8] = Ag[(size_t)row * 256 + kv + c8];
      Bs[row * 9 + c8] = Bg[(size_t)row * 256 + kv + c8];
    }
    __syncthreads();
    #pragma unroll
    for (int kk = 0; kk < 2; kk++) {
      bf16x8 a[4], b[4];
      #pragma unroll
      for (int i = 0; i < 4; i++)
        a[i] = as_frag(As[(wm * 64 + i * 16 + l16) * 9 + kk * 4 + quad]);
      #pragma unroll
      for (int i = 0; i < 4; i++)
        b[i] = as_frag(Bs[(wn * 64 + i * 16 + l16) * 9 + kk * 4 + quad]);
      #pragma unroll
      for (int i = 0; i < 4; i++)
        #pragma unroll
        for (int j = 0; j < 4; j++)
          acc[i][j] = __builtin_amdgcn_mfma_f32_16x16x32_bf16(a[i], b[j], acc[i][j], 0, 0, 0);
    }
    __syncthreads();
  }

  // epilogue: bias add + write
  #pragma unroll
  for (int i = 0; i < 4; i++) {
    #pragma unroll
    for (int j = 0; j < 4; j++) {
      int col = wn * 64 + j * 16 + l16;       // e
      float bb = bias[col];
      #pragma unroll
      for (int r = 0; r < 4; r++) {
        int row = mt * 128 + wm * 64 + i * 16 + quad * 4 + r;  // 0..4095
        int b_ = row >> 11, p = row & 2047;
        int bh = b_ * NHEADS + h;
        ushort val = f2bf(acc[i][j][r] + bb);
        if (which == 2) {
          Vt[((size_t)bh * DHEAD + col) * SEQ + p] = val;     // [bh][e][pos]
        } else {
          ushort* Out = (which == 0) ? Qo : Ko;
          Out[((size_t)bh * SEQ + p) * DHEAD + col] = val;    // [bh][pos][e]
        }
      }
    }
  }
}

// ---------------------------------------------------------------------------
// Flash attention (causal). Grid (qtile=32, bh=32). Block 256 = 4 waves.
// Q,K: [bh][pos][128] bf16; Vt: [bh][128][pos]; Z out: [4096][2048] bf16
// ---------------------------------------------------------------------------
__global__ __launch_bounds__(256, 2) void flash_attn(
    const ushort* __restrict__ Q, const ushort* __restrict__ K,
    const ushort* __restrict__ Vt, ushort* __restrict__ Z)
{
  int qt = blockIdx.x;   // 0..31
  int bh = blockIdx.y;   // 0..31
  const u32x4* Qg = (const u32x4*)(Q + (size_t)bh * SEQ * DHEAD);  // [2048][16]
  const u32x4* Kg = (const u32x4*)(K + (size_t)bh * SEQ * DHEAD);
  const u32x4* Vg = (const u32x4*)(Vt + (size_t)bh * DHEAD * SEQ); // [128][256]

  __shared__ u32x4 Qs[64 * 17];
  __shared__ u32x4 Ks[64 * 17];
  __shared__ u32x4 Vs[128 * 9];
  __shared__ u32x4 Ps[64 * 9];

  int tid = threadIdx.x, lane = tid & 63, w = tid >> 6;
  int l16 = lane & 15, quad = lane >> 4;
  int q0 = qt * 64;

  // stage Q tile (64 rows x 16 u32x4)
  #pragma unroll
  for (int i = 0; i < 4; i++) {
    int v = tid + i * 256;
    int row = v >> 4, c = v & 15;
    Qs[row * 17 + c] = Qg[(size_t)(q0 + row) * 16 + c];
  }

  float m_i[4], l_i[4];
  #pragma unroll
  for (int i = 0; i < 4; i++) { m_i[i] = -1e30f; l_i[i] = 0.0f; }
  f32x4 zacc[8] = {};

  for (int j = 0; j <= qt; j++) {
    int k0 = j * 64;
    __syncthreads();  // Qs visible (j=0); prior PV done with Ks/Vs/Ps
    #pragma unroll
    for (int i = 0; i < 4; i++) {
      int v = tid + i * 256;
      int row = v >> 4, c = v & 15;
      Ks[row * 17 + c] = Kg[(size_t)(k0 + row) * 16 + c];
    }
    #pragma unroll
    for (int i = 0; i < 4; i++) {
      int v = tid + i * 256;
      int row = v >> 3, c = v & 7;
      Vs[row * 9 + c] = Vg[(size_t)row * 256 + (k0 >> 3) + c];
    }
    __syncthreads();

    // S = Q K^T  (wave w: q rows 16w..16w+15, keys 0..63)
    f32x4 s[4] = {};
    #pragma unroll
    for (int kk = 0; kk < 4; kk++) {
      bf16x8 a = as_frag(Qs[(w * 16 + l16) * 17 + kk * 4 + quad]);
      #pragma unroll
      for (int n = 0; n < 4; n++) {
        bf16x8 b = as_frag(Ks[(n * 16 + l16) * 17 + kk * 4 + quad]);
        s[n] = __builtin_amdgcn_mfma_f32_16x16x32_bf16(a, b, s[n], 0, 0, 0);
      }
    }
    // scale + causal mask (only diagonal chunk)
    #pragma unroll
    for (int n = 0; n < 4; n++)
      #pragma unroll
      for (int i = 0; i < 4; i++) {
        float v = s[n][i] * RSCALE;
        if (j == qt) {
          int qrow = 16 * w + quad * 4 + i;
          int krow = n * 16 + l16;
          if (krow > qrow) v = -1e30f;
        }
        s[n][i] = v;
      }
    // row max across 4 regs + 16 lanes
    float mx[4];
    #pragma unroll
    for (int i = 0; i < 4; i++)
      mx[i] = fmaxf(fmaxf(s[0][i], s[1][i]), fmaxf(s[2][i], s[3][i]));
    #pragma unroll
    for (int off = 1; off < 16; off <<= 1)
      #pragma unroll
      for (int i = 0; i < 4; i++)
        mx[i] = fmaxf(mx[i], __shfl_xor(mx[i], off, 64));

    float alpha[4], rsum[4];
    #pragma unroll
    for (int i = 0; i < 4; i++) {
      float mn = fmaxf(m_i[i], mx[i]);
      alpha[i] = __expf(m_i[i] - mn);
      m_i[i] = mn;
      rsum[i] = 0.0f;
    }
    // P = exp(s - m), write bf16 to LDS (A-operand layout round-trip)
    ushort* Pus = (ushort*)Ps;
    #pragma unroll
    for (int n = 0; n < 4; n++)
      #pragma unroll
      for (int i = 0; i < 4; i++) {
        float p = __expf(s[n][i] - m_i[i]);
        rsum[i] += p;
        int row = 16 * w + quad * 4 + i, col = n * 16 + l16;
        Pus[row * 72 + col] = f2bf(p);
      }
    #pragma unroll
    for (int off = 1; off < 16; off <<= 1)
      #pragma unroll
      for (int i = 0; i < 4; i++)
        rsum[i] += __shfl_xor(rsum[i], off, 64);
    #pragma unroll
    for (int i = 0; i < 4; i++) l_i[i] = l_i[i] * alpha[i] + rsum[i];
    // rescale running O
    #pragma unroll
    for (int n = 0; n < 8; n++)
      #pragma unroll
      for (int i = 0; i < 4; i++) zacc[n][i] *= alpha[i];

    __syncthreads();  // Ps visible

    // O += P V : wave w rows 16w..16w+15, all 128 e
    #pragma unroll
    for (int kk = 0; kk < 2; kk++) {
      bf16x8 a = as_frag(Ps[(w * 16 + l16) * 9 + kk * 4 + quad]);
      #pragma unroll
      for (int n = 0; n < 8; n++) {
        bf16x8 b = as_frag(Vs[(n * 16 + l16) * 9 + kk * 4 + quad]);
        zacc[n] = __builtin_amdgcn_mfma_f32_16x16x32_bf16(a, b, zacc[n], 0, 0, 0);
      }
    }
  }

  // epilogue: Z[b*2048+pos][h*128+e] = zacc / l  (bf16)
  int b_ = bh >> 4, h = bh & 15;
  #pragma unroll
  for (int n = 0; n < 8; n++)
    #pragma unroll
    for (int i = 0; i < 4; i++) {
      int row = q0 + 16 * w + quad * 4 + i;
      int col = h * DHEAD + n * 16 + l16;
      Z[((size_t)(b_ * SEQ + row)) * DMODEL + col] = f2bf(zacc[n][i] / l_i[i]);
    }
}

// ---------------------------------------------------------------------------
// Output projection: out[4096][2048] f32 = Z[4096][2048] bf16 * WoT + bO
// WoT [2048 n][2048 (h,e)] bf16
// ---------------------------------------------------------------------------
__global__ __launch_bounds__(256, 2) void gemm_out(
    const ushort* __restrict__ Zin, const ushort* __restrict__ WoT,
    const float* __restrict__ bO, float* __restrict__ out)
{
  int mt = blockIdx.x, ntile = blockIdx.y;
  __shared__ u32x4 As[128 * 9];
  __shared__ u32x4 Bs[128 * 9];
  int tid = threadIdx.x, lane = tid & 63, wid = tid >> 6;
  int wm = wid >> 1, wn = wid & 1;
  int l16 = lane & 15, quad = lane >> 4;

  const u32x4* Ag = (const u32x4*)Zin + (size_t)(mt * 128) * 256;
  const u32x4* Bg = (const u32x4*)WoT + (size_t)(ntile * 128) * 256;

  f32x4 acc[4][4] = {};
  for (int k0 = 0; k0 < DMODEL; k0 += 64) {
    int kv = k0 >> 3;
    #pragma unroll
    for (int i = 0; i < 4; i++) {
      int v = tid + i * 256;
      int row = v >> 3, c8 = v & 7;
      As[row * 9 + c8] = Ag[(size_t)row * 256 + kv + c8];
      Bs[row * 9 + c8] = Bg[(size_t)row * 256 + kv + c8];
    }
    __syncthreads();
    #pragma unroll
    for (int kk = 0; kk < 2; kk++) {
      bf16x8 a[4], b[4];
      #pragma unroll
      for (int i = 0; i < 4; i++)
        a[i] = as_frag(As[(wm * 64 + i * 16 + l16) * 9 + kk * 4 + quad]);
      #pragma unroll
      for (int i = 0; i < 4; i++)
        b[i] = as_frag(Bs[(wn * 64 + i * 16 + l16) * 9 + kk * 4 + quad]);
      #pragma unroll
      for (int i = 0; i < 4; i++)
        #pragma unroll
        for (int j = 0; j < 4; j++)
          acc[i][j] = __builtin_amdgcn_mfma_f32_16x16x32_bf16(a[i], b[j], acc[i][j], 0, 0, 0);
    }
    __syncthreads();
  }
  #pragma unroll
  for (int i = 0; i < 4; i++) {
    #pragma unroll
    for (int j = 0; j < 4; j++) {
      int col = ntile * 128 + wn * 64 + j * 16 + l16;
      float bb = bO[col];
      #pragma unroll
      for (int r = 0; r < 4; r++) {
        int row = mt * 128 + wm * 64 + i * 16 + quad * 4 + r;
        out[(size_t)row * DMODEL + col] = acc[i][j][r] + bb;
      }
    }
  }
}

// ---------------------------------------------------------------------------
extern "C" void kernel_launch(void* const* d_in, const int* in_sizes, int n_in,
                              void* d_out, int out_size, void* d_ws, size_t ws_size,
                              hipStream_t stream)
{
  const float* x  = (const float*)d_in[0];
  const float* Wq = (const float*)d_in[1];
  const float* Wk = (const float*)d_in[2];
  const float* Wv = (const float*)d_in[3];
  const float* Wo = (const float*)d_in[4];
  const float* bQ = (const float*)d_in[5];
  const float* bK = (const float*)d_in[6];
  const float* bV = (const float*)d_in[7];
  const float* bO = (const float*)d_in[8];
  float* out = (float*)d_out;

  // workspace layout (bf16/ushort elements); total ~117 MB
  ushort* ws = (ushort*)d_ws;
  const size_t WSZ = (size_t)NHEADS * DHEAD * DMODEL;       // 4,194,304
  const size_t QSZ = (size_t)BATCH * NHEADS * SEQ * DHEAD;  // 8,388,608
  ushort* xb  = ws;                                // 8,388,608
  ushort* WqT = xb + (size_t)MROWS * DMODEL;
  ushort* WkT = WqT + WSZ;
  ushort* WvT = WkT + WSZ;
  ushort* WoT = WvT + WSZ;
  ushort* Qb  = WoT + (size_t)DMODEL * DMODEL;
  ushort* Kb  = Qb + QSZ;
  ushort* VtB = Kb + QSZ;
  ushort* Zb  = VtB + QSZ;

  dim3 tb(256);
  // x fp32 -> bf16
  convert_f32_bf16<<<dim3((MROWS * DMODEL / 4 + 255) / 256), tb, 0, stream>>>(
      x, xb, MROWS * DMODEL / 4);
  // weight transposes + convert: W[h][d][e] -> WT[h][e][d]; Wo[(h,e)][n] -> WoT[n][(h,e)]
  transpose_f32_bf16<<<dim3(4, 64, 16), tb, 0, stream>>>(Wq, WqT, DMODEL, DHEAD);
  transpose_f32_bf16<<<dim3(4, 64, 16), tb, 0, stream>>>(Wk, WkT, DMODEL, DHEAD);
  transpose_f32_bf16<<<dim3(4, 64, 16), tb, 0, stream>>>(Wv, WvT, DMODEL, DHEAD);
  transpose_f32_bf16<<<dim3(64, 64, 1), tb, 0, stream>>>(Wo, WoT, DMODEL, DMODEL);

  gemm_qkv<<<dim3(32, 16, 3), tb, 0, stream>>>(xb, WqT, WkT, WvT, bQ, bK, bV,
                                               Qb, Kb, VtB);

  flash_attn<<<dim3(32, 32), tb, 0, stream>>>(Qb, Kb, VtB, Zb);

  gemm_out<<<dim3(32, 16), tb, 0, stream>>>(Zb, WoT, bO, out);
}

// Round 3
// 389.945 us; speedup vs baseline: 1.3301x; 1.3301x over previous
//
#include <hip/hip_runtime.h>

typedef unsigned int uint;
typedef unsigned short ushort;
typedef __bf16 bf16x8 __attribute__((ext_vector_type(8)));
typedef float f32x4 __attribute__((ext_vector_type(4)));
typedef uint u32x4 __attribute__((ext_vector_type(4)));

#define DEV static __device__ __forceinline__

#define BATCH 2
#define SEQ 2048
#define DMODEL 2048
#define NHEADS 16
#define DHEAD 128
#define MROWS (BATCH*SEQ)           // 4096
#define RSCALE 0.08838834764831845f // 1/sqrt(128)

DEV bf16x8 as_frag(u32x4 v) { return __builtin_bit_cast(bf16x8, v); }
DEV ushort f2bf(float f) {
  uint u = __builtin_bit_cast(uint, f);
  u += 0x7fffu + ((u >> 16) & 1u);   // RNE
  return (ushort)(u >> 16);
}
DEV u32x4 lds_ld16(const ushort* p) { return *(const u32x4*)p; }

// async global->LDS, 16B per lane; LDS dest = uniform base + lane*16
DEV void async_cp16(const ushort* g, ushort* l) {
  __builtin_amdgcn_global_load_lds(
      (const __attribute__((address_space(1))) uint*)g,
      (__attribute__((address_space(3))) uint*)l, 16, 0, 0);
}

// ---------------------------------------------------------------------------
// Flat fp32 -> bf16 conversion (x)
// ---------------------------------------------------------------------------
__global__ __launch_bounds__(256) void convert_f32_bf16(
    const float* __restrict__ src, ushort* __restrict__ dst, int n4)
{
  int i = blockIdx.x * 256 + threadIdx.x;
  if (i >= n4) return;
  const float4* s4 = (const float4*)src;
  float4 v = s4[i];
  union { ushort u[4]; uint2 w; } o;
  o.u[0] = f2bf(v.x); o.u[1] = f2bf(v.y); o.u[2] = f2bf(v.z); o.u[3] = f2bf(v.w);
  ((uint2*)dst)[i] = o.w;
}

// ---------------------------------------------------------------------------
// fp32 2D transpose + convert: src[slice][R][C] f32 -> dst[slice][C][R] bf16
// ---------------------------------------------------------------------------
__global__ __launch_bounds__(256) void transpose_f32_bf16(
    const float* __restrict__ src, ushort* __restrict__ dst, int R, int C)
{
  __shared__ ushort t[32][33];
  size_t slice = (size_t)blockIdx.z * R * C;
  src += slice; dst += slice;
  int c0 = blockIdx.x * 32, r0 = blockIdx.y * 32;
  int x = threadIdx.x & 31, y = threadIdx.x >> 5;
  #pragma unroll
  for (int i = 0; i < 32; i += 8)
    t[y + i][x] = f2bf(src[(size_t)(r0 + y + i) * C + (c0 + x)]);
  __syncthreads();
  #pragma unroll
  for (int i = 0; i < 32; i += 8)
    dst[(size_t)(c0 + y + i) * R + (r0 + x)] = t[x][y + i];
}

// ---------------------------------------------------------------------------
// QKV projection GEMM, m97-style: 128x128 tile, BK=64, async staging +
// XOR-swizzled unpadded LDS.
// A = xb [4096][2048] bf16, Bt = W^T per head [128 e][2048 d] bf16
// Q out pre-scaled by 1/sqrt(d); V out written transposed Vt[bh][e][pos].
// ---------------------------------------------------------------------------
__global__ __launch_bounds__(256, 3) void gemm_qkv(
    const ushort* __restrict__ xb,
    const ushort* __restrict__ WqT, const ushort* __restrict__ WkT,
    const ushort* __restrict__ WvT,
    const float* __restrict__ bQ, const float* __restrict__ bK,
    const float* __restrict__ bV,
    ushort* __restrict__ Qo, ushort* __restrict__ Ko, ushort* __restrict__ Vt)
{
  int mt = blockIdx.x;       // 0..31
  int h  = blockIdx.y;       // 0..15
  int which = blockIdx.z;    // 0:Q 1:K 2:V
  const ushort* Bt = (which == 0) ? WqT : (which == 1) ? WkT : WvT;
  const float* bias = (which == 0) ? bQ : (which == 1) ? bK : bV;
  Bt += (size_t)h * DHEAD * DMODEL;
  bias += h * DHEAD;

  __shared__ __align__(16) ushort As[128 * 64];  // 16 KB, unit-swizzled
  __shared__ __align__(16) ushort Bs[128 * 64];

  int tid = threadIdx.x, lane = tid & 63, w = tid >> 6;
  int wm = w >> 1, wn = w & 1;
  int l16 = lane & 15, quad = lane >> 4;

  const ushort* Ag = xb + (size_t)(mt * 128) * DMODEL;

  // staging geometry: chunk c = w*4+t covers rows c*8..c*8+7 (8 units/row)
  int soff[4]; int sc[4];
  #pragma unroll
  for (int t = 0; t < 4; t++) {
    int c = w * 4 + t;
    int r = c * 8 + (lane >> 3);
    int p = lane & 7;
    int g = p ^ (r & 7);
    soff[t] = r * DMODEL + g * 8;
    sc[t] = c * 512;   // ushort offset of chunk base in LDS
  }

  f32x4 acc[4][4] = {};

  for (int k0 = 0; k0 < DMODEL; k0 += 64) {
    __syncthreads();
    #pragma unroll
    for (int t = 0; t < 4; t++) {
      async_cp16(Ag + soff[t] + k0, As + sc[t]);
      async_cp16(Bt + soff[t] + k0, Bs + sc[t]);
    }
    __syncthreads();
    #pragma unroll
    for (int kk = 0; kk < 2; kk++) {
      bf16x8 a[4], b[4];
      #pragma unroll
      for (int i = 0; i < 4; i++) {
        int row = wm * 64 + i * 16 + l16;
        int p = (kk * 4 + quad) ^ (l16 & 7);
        a[i] = as_frag(lds_ld16(As + row * 64 + p * 8));
      }
      #pragma unroll
      for (int i = 0; i < 4; i++) {
        int row = wn * 64 + i * 16 + l16;
        int p = (kk * 4 + quad) ^ (l16 & 7);
        b[i] = as_frag(lds_ld16(Bs + row * 64 + p * 8));
      }
      #pragma unroll
      for (int i = 0; i < 4; i++)
        #pragma unroll
        for (int j = 0; j < 4; j++)
          acc[i][j] = __builtin_amdgcn_mfma_f32_16x16x32_bf16(a[i], b[j], acc[i][j], 0, 0, 0);
    }
  }

  float scale = (which == 0) ? RSCALE : 1.0f;
  #pragma unroll
  for (int i = 0; i < 4; i++) {
    #pragma unroll
    for (int j = 0; j < 4; j++) {
      int col = wn * 64 + j * 16 + l16;       // e
      float bb = bias[col];
      #pragma unroll
      for (int r = 0; r < 4; r++) {
        int row = mt * 128 + wm * 64 + i * 16 + quad * 4 + r;  // 0..4095
        int b_ = row >> 11, p = row & 2047;
        int bh = b_ * NHEADS + h;
        ushort val = f2bf((acc[i][j][r] + bb) * scale);
        if (which == 2) {
          Vt[((size_t)bh * DHEAD + col) * SEQ + p] = val;     // [bh][e][pos]
        } else {
          ushort* Out = (which == 0) ? Qo : Ko;
          Out[((size_t)bh * SEQ + p) * DHEAD + col] = val;    // [bh][pos][e]
        }
      }
    }
  }
}

// ---------------------------------------------------------------------------
// Flash attention (causal), balanced pairing: block a does qtiles {31-a, a}.
// Q pre-scaled. Q in registers; K/V async-staged w/ swizzle. 3 blocks/CU.
// ---------------------------------------------------------------------------
__global__ __launch_bounds__(256, 3) void flash_attn(
    const ushort* __restrict__ Q, const ushort* __restrict__ K,
    const ushort* __restrict__ Vt, ushort* __restrict__ Z)
{
  int a  = blockIdx.x;   // 0..15
  int bh = blockIdx.y;   // 0..31
  const ushort* Qg = Q + (size_t)bh * SEQ * DHEAD;   // [2048][128]
  const ushort* Kg = K + (size_t)bh * SEQ * DHEAD;
  const ushort* Vg = Vt + (size_t)bh * DHEAD * SEQ;  // [128][2048]

  __shared__ __align__(16) ushort Ks[64 * 128];  // 16 KB: row=key, 16 units swz
  __shared__ __align__(16) ushort Vs[128 * 64];  // 16 KB: row=e,   8 units swz
  __shared__ __align__(16) ushort Ps[64 * 72];   // 9 KB padded

  int tid = threadIdx.x, lane = tid & 63, w = tid >> 6;
  int l16 = lane & 15, quad = lane >> 4;

  // staging geometry
  int kOff[4], kLds[4], vOff[4], vLds[4];
  #pragma unroll
  for (int t = 0; t < 4; t++) {
    int c = w * 4 + t;
    // K: chunk = 4 rows x 16 units
    int rk = c * 4 + (lane >> 4);
    int pk = lane & 15;
    int gk = (pk & 8) | ((pk & 7) ^ (rk & 7));
    kOff[t] = rk * DHEAD + gk * 8;
    kLds[t] = c * 512;
    // V: chunk = 8 rows x 8 units
    int ev = c * 8 + (lane >> 3);
    int pv = lane & 7;
    int gv = pv ^ (ev & 7);
    vOff[t] = ev * SEQ + gv * 8;
    vLds[t] = c * 512;
  }

  #pragma unroll
  for (int ph = 0; ph < 2; ph++) {
    int qt = ph ? a : (31 - a);
    int q0 = qt * 64;

    // Q fragments: wave w owns q rows q0+16w..+15
    bf16x8 qf[4];
    int qrow = q0 + w * 16 + l16;
    #pragma unroll
    for (int kb = 0; kb < 4; kb++)
      qf[kb] = as_frag(*(const u32x4*)(Qg + qrow * DHEAD + kb * 32 + quad * 8));

    float m_i[4], l_i[4];
    #pragma unroll
    for (int i = 0; i < 4; i++) { m_i[i] = -1e30f; l_i[i] = 0.0f; }
    f32x4 zacc[8] = {};

    for (int j = 0; j <= qt; j++) {
      int k0 = j * 64;
      __syncthreads();  // prior chunk's LDS reads done
      #pragma unroll
      for (int t = 0; t < 4; t++) {
        async_cp16(Kg + k0 * DHEAD + kOff[t], Ks + kLds[t]);
        async_cp16(Vg + k0 + vOff[t], Vs + vLds[t]);
      }
      __syncthreads();  // staging visible (vmcnt drained by barrier)

      // S = Q K^T
      f32x4 s[4] = {};
      #pragma unroll
      for (int kb = 0; kb < 4; kb++) {
        #pragma unroll
        for (int n = 0; n < 4; n++) {
          int r = n * 16 + l16;
          int ug = kb * 4 + quad;
          int p = (ug & 8) | ((ug & 7) ^ (r & 7));
          bf16x8 b = as_frag(lds_ld16(Ks + r * 128 + p * 8));
          s[n] = __builtin_amdgcn_mfma_f32_16x16x32_bf16(qf[kb], b, s[n], 0, 0, 0);
        }
      }
      // causal mask only on the diagonal chunk (Q already scaled)
      if (j == qt) {
        #pragma unroll
        for (int n = 0; n < 4; n++)
          #pragma unroll
          for (int i = 0; i < 4; i++) {
            int qr = 16 * w + quad * 4 + i;
            int kr = n * 16 + l16;
            if (kr > qr) s[n][i] = -1e30f;
          }
      }
      // row max
      float mx[4];
      #pragma unroll
      for (int i = 0; i < 4; i++)
        mx[i] = fmaxf(fmaxf(s[0][i], s[1][i]), fmaxf(s[2][i], s[3][i]));
      #pragma unroll
      for (int off = 1; off < 16; off <<= 1)
        #pragma unroll
        for (int i = 0; i < 4; i++)
          mx[i] = fmaxf(mx[i], __shfl_xor(mx[i], off, 64));

      float alpha[4], rsum[4];
      #pragma unroll
      for (int i = 0; i < 4; i++) {
        float mn = fmaxf(m_i[i], mx[i]);
        alpha[i] = __expf(m_i[i] - mn);
        m_i[i] = mn;
        rsum[i] = 0.0f;
      }
      #pragma unroll
      for (int n = 0; n < 4; n++)
        #pragma unroll
        for (int i = 0; i < 4; i++) {
          float p = __expf(s[n][i] - m_i[i]);
          rsum[i] += p;
          int row = 16 * w + quad * 4 + i, col = n * 16 + l16;
          Ps[row * 72 + col] = f2bf(p);
        }
      #pragma unroll
      for (int off = 1; off < 16; off <<= 1)
        #pragma unroll
        for (int i = 0; i < 4; i++)
          rsum[i] += __shfl_xor(rsum[i], off, 64);
      #pragma unroll
      for (int i = 0; i < 4; i++) l_i[i] = l_i[i] * alpha[i] + rsum[i];
      #pragma unroll
      for (int n = 0; n < 8; n++)
        #pragma unroll
        for (int i = 0; i < 4; i++) zacc[n][i] *= alpha[i];

      __syncthreads();  // Ps visible

      // O += P V
      #pragma unroll
      for (int kk = 0; kk < 2; kk++) {
        bf16x8 af = as_frag(lds_ld16(Ps + (w * 16 + l16) * 72 + (kk * 4 + quad) * 8));
        #pragma unroll
        for (int n = 0; n < 8; n++) {
          int e = n * 16 + l16;
          int ug = kk * 4 + quad;
          int p = ug ^ (e & 7);
          bf16x8 b = as_frag(lds_ld16(Vs + e * 64 + p * 8));
          zacc[n] = __builtin_amdgcn_mfma_f32_16x16x32_bf16(af, b, zacc[n], 0, 0, 0);
        }
      }
    }

    // epilogue: Z[b*2048+pos][h*128+e] = zacc / l  (bf16)
    int b_ = bh >> 4, h = bh & 15;
    #pragma unroll
    for (int n = 0; n < 8; n++)
      #pragma unroll
      for (int i = 0; i < 4; i++) {
        int row = q0 + 16 * w + quad * 4 + i;
        int col = h * DHEAD + n * 16 + l16;
        Z[((size_t)(b_ * SEQ + row)) * DMODEL + col] = f2bf(zacc[n][i] / l_i[i]);
      }
  }
}

// ---------------------------------------------------------------------------
// Output projection (m97-style core): out f32 = Z bf16 * WoT + bO
// ---------------------------------------------------------------------------
__global__ __launch_bounds__(256, 3) void gemm_out(
    const ushort* __restrict__ Zin, const ushort* __restrict__ WoT,
    const float* __restrict__ bO, float* __restrict__ out)
{
  int mt = blockIdx.x, ntile = blockIdx.y;
  __shared__ __align__(16) ushort As[128 * 64];
  __shared__ __align__(16) ushort Bs[128 * 64];
  int tid = threadIdx.x, lane = tid & 63, w = tid >> 6;
  int wm = w >> 1, wn = w & 1;
  int l16 = lane & 15, quad = lane >> 4;

  const ushort* Ag = Zin + (size_t)(mt * 128) * DMODEL;
  const ushort* Bg = WoT + (size_t)(ntile * 128) * DMODEL;

  int soff[4]; int sc[4];
  #pragma unroll
  for (int t = 0; t < 4; t++) {
    int c = w * 4 + t;
    int r = c * 8 + (lane >> 3);
    int p = lane & 7;
    int g = p ^ (r & 7);
    soff[t] = r * DMODEL + g * 8;
    sc[t] = c * 512;
  }

  f32x4 acc[4][4] = {};
  for (int k0 = 0; k0 < DMODEL; k0 += 64) {
    __syncthreads();
    #pragma unroll
    for (int t = 0; t < 4; t++) {
      async_cp16(Ag + soff[t] + k0, As + sc[t]);
      async_cp16(Bg + soff[t] + k0, Bs + sc[t]);
    }
    __syncthreads();
    #pragma unroll
    for (int kk = 0; kk < 2; kk++) {
      bf16x8 a[4], b[4];
      #pragma unroll
      for (int i = 0; i < 4; i++) {
        int row = wm * 64 + i * 16 + l16;
        int p = (kk * 4 + quad) ^ (l16 & 7);
        a[i] = as_frag(lds_ld16(As + row * 64 + p * 8));
      }
      #pragma unroll
      for (int i = 0; i < 4; i++) {
        int row = wn * 64 + i * 16 + l16;
        int p = (kk * 4 + quad) ^ (l16 & 7);
        b[i] = as_frag(lds_ld16(Bs + row * 64 + p * 8));
      }
      #pragma unroll
      for (int i = 0; i < 4; i++)
        #pragma unroll
        for (int j = 0; j < 4; j++)
          acc[i][j] = __builtin_amdgcn_mfma_f32_16x16x32_bf16(a[i], b[j], acc[i][j], 0, 0, 0);
    }
  }
  #pragma unroll
  for (int i = 0; i < 4; i++) {
    #pragma unroll
    for (int j = 0; j < 4; j++) {
      int col = ntile * 128 + wn * 64 + j * 16 + l16;
      float bb = bO[col];
      #pragma unroll
      for (int r = 0; r < 4; r++) {
        int row = mt * 128 + wm * 64 + i * 16 + quad * 4 + r;
        out[(size_t)row * DMODEL + col] = acc[i][j][r] + bb;
      }
    }
  }
}

// ---------------------------------------------------------------------------
extern "C" void kernel_launch(void* const* d_in, const int* in_sizes, int n_in,
                              void* d_out, int out_size, void* d_ws, size_t ws_size,
                              hipStream_t stream)
{
  const float* x  = (const float*)d_in[0];
  const float* Wq = (const float*)d_in[1];
  const float* Wk = (const float*)d_in[2];
  const float* Wv = (const float*)d_in[3];
  const float* Wo = (const float*)d_in[4];
  const float* bQ = (const float*)d_in[5];
  const float* bK = (const float*)d_in[6];
  const float* bV = (const float*)d_in[7];
  const float* bO = (const float*)d_in[8];
  float* out = (float*)d_out;

  ushort* ws = (ushort*)d_ws;
  const size_t WSZ = (size_t)NHEADS * DHEAD * DMODEL;       // 4,194,304
  const size_t QSZ = (size_t)BATCH * NHEADS * SEQ * DHEAD;  // 8,388,608
  ushort* xb  = ws;
  ushort* WqT = xb + (size_t)MROWS * DMODEL;
  ushort* WkT = WqT + WSZ;
  ushort* WvT = WkT + WSZ;
  ushort* WoT = WvT + WSZ;
  ushort* Qb  = WoT + (size_t)DMODEL * DMODEL;
  ushort* Kb  = Qb + QSZ;
  ushort* VtB = Kb + QSZ;
  ushort* Zb  = VtB + QSZ;

  dim3 tb(256);
  convert_f32_bf16<<<dim3(MROWS * DMODEL / 4 / 256), tb, 0, stream>>>(
      x, xb, MROWS * DMODEL / 4);
  transpose_f32_bf16<<<dim3(4, 64, 16), tb, 0, stream>>>(Wq, WqT, DMODEL, DHEAD);
  transpose_f32_bf16<<<dim3(4, 64, 16), tb, 0, stream>>>(Wk, WkT, DMODEL, DHEAD);
  transpose_f32_bf16<<<dim3(4, 64, 16), tb, 0, stream>>>(Wv, WvT, DMODEL, DHEAD);
  transpose_f32_bf16<<<dim3(64, 64, 1), tb, 0, stream>>>(Wo, WoT, DMODEL, DMODEL);

  gemm_qkv<<<dim3(32, 16, 3), tb, 0, stream>>>(xb, WqT, WkT, WvT, bQ, bK, bV,
                                               Qb, Kb, VtB);

  flash_attn<<<dim3(16, 32), tb, 0, stream>>>(Qb, Kb, VtB, Zb);

  gemm_out<<<dim3(32, 16), tb, 0, stream>>>(Zb, WoT, bO, out);
}

// Round 5
// 374.117 us; speedup vs baseline: 1.3864x; 1.0423x over previous
//
#include <hip/hip_runtime.h>

typedef unsigned int uint;
typedef unsigned short ushort;
typedef __bf16 bf16x8 __attribute__((ext_vector_type(8)));
typedef float f32x4 __attribute__((ext_vector_type(4)));
typedef uint u32x4 __attribute__((ext_vector_type(4)));

#define DEV static __device__ __forceinline__

#define BATCH 2
#define SEQ 2048
#define DMODEL 2048
#define NHEADS 16
#define DHEAD 128
#define MROWS (BATCH*SEQ)           // 4096
#define RSCALE 0.08838834764831845f // 1/sqrt(128)
#define LOG2E  1.4426950408889634f

DEV float fast_exp2(float x) { return __builtin_amdgcn_exp2f(x); }

DEV bf16x8 as_frag(u32x4 v) { return __builtin_bit_cast(bf16x8, v); }
DEV ushort f2bf(float f) {
  uint u = __builtin_bit_cast(uint, f);
  u += 0x7fffu + ((u >> 16) & 1u);   // RNE
  return (ushort)(u >> 16);
}
DEV u32x4 lds_ld16(const ushort* p) { return *(const u32x4*)p; }

// async global->LDS, 16B per lane; LDS dest = wave-uniform base + lane*16
DEV void async_cp16(const ushort* g, ushort* l) {
  __builtin_amdgcn_global_load_lds(
      (const __attribute__((address_space(1))) uint*)g,
      (__attribute__((address_space(3))) uint*)l, 16, 0, 0);
}

// ---------------------------------------------------------------------------
// Fused preprocessing: x f32->bf16 convert + 4 weight transposes (f32->bf16)
// block ranges: [0,8192) convert; [8192,20480) Wq/Wk/Wv T; [20480,24576) Wo T
// ---------------------------------------------------------------------------
__global__ __launch_bounds__(256) void prep(
    const float* __restrict__ x,
    const float* __restrict__ Wq, const float* __restrict__ Wk,
    const float* __restrict__ Wv, const float* __restrict__ Wo,
    ushort* __restrict__ xb, ushort* __restrict__ WqT,
    ushort* __restrict__ WkT, ushort* __restrict__ WvT,
    ushort* __restrict__ WoT)
{
  int id = blockIdx.x;
  if (id < 8192) {
    int i = id * 256 + threadIdx.x;       // n4 = 2,097,152 exactly
    float4 v = ((const float4*)x)[i];
    union { ushort u[4]; uint2 w; } o;
    o.u[0] = f2bf(v.x); o.u[1] = f2bf(v.y); o.u[2] = f2bf(v.z); o.u[3] = f2bf(v.w);
    ((uint2*)xb)[i] = o.w;
    return;
  }
  __shared__ ushort t[32][33];
  id -= 8192;
  const float* src; ushort* dst; int R, C, c0, r0;
  if (id < 12288) {
    int which = id >> 12;                 // /4096
    int r = id & 4095;
    int slice = r >> 8;
    int rem = r & 255;
    int ty = rem >> 2, tx = rem & 3;
    const float* S[3] = {Wq, Wk, Wv};
    ushort* D[3] = {WqT, WkT, WvT};
    src = S[which] + (size_t)slice * DMODEL * DHEAD;
    dst = D[which] + (size_t)slice * DMODEL * DHEAD;
    R = DMODEL; C = DHEAD; c0 = tx * 32; r0 = ty * 32;
  } else {
    id -= 12288;
    int tx = id & 63, ty = id >> 6;
    src = Wo; dst = WoT; R = DMODEL; C = DMODEL; c0 = tx * 32; r0 = ty * 32;
  }
  int xx = threadIdx.x & 31, yy = threadIdx.x >> 5;
  #pragma unroll
  for (int i = 0; i < 32; i += 8)
    t[yy + i][xx] = f2bf(src[(size_t)(r0 + yy + i) * C + (c0 + xx)]);
  __syncthreads();
  #pragma unroll
  for (int i = 0; i < 32; i += 8)
    dst[(size_t)(c0 + yy + i) * R + (r0 + xx)] = t[xx][yy + i];
}

// ---------------------------------------------------------------------------
// QKV projection GEMM (m97-style). Q pre-scaled by RSCALE*LOG2E (exp2 domain);
// V written transposed Vt[bh][e][pos].
// ---------------------------------------------------------------------------
__global__ __launch_bounds__(256, 4) void gemm_qkv(
    const ushort* __restrict__ xb,
    const ushort* __restrict__ WqT, const ushort* __restrict__ WkT,
    const ushort* __restrict__ WvT,
    const float* __restrict__ bQ, const float* __restrict__ bK,
    const float* __restrict__ bV,
    ushort* __restrict__ Qo, ushort* __restrict__ Ko, ushort* __restrict__ Vt)
{
  int mt = blockIdx.x;       // 0..31
  int h  = blockIdx.y;       // 0..15
  int which = blockIdx.z;    // 0:Q 1:K 2:V
  const ushort* Bt = (which == 0) ? WqT : (which == 1) ? WkT : WvT;
  const float* bias = (which == 0) ? bQ : (which == 1) ? bK : bV;
  Bt += (size_t)h * DHEAD * DMODEL;
  bias += h * DHEAD;

  __shared__ __align__(16) ushort As[128 * 64];
  __shared__ __align__(16) ushort Bs[128 * 64];

  int tid = threadIdx.x, lane = tid & 63, w = tid >> 6;
  int wm = w >> 1, wn = w & 1;
  int l16 = lane & 15, quad = lane >> 4;

  const ushort* Ag = xb + (size_t)(mt * 128) * DMODEL;

  int soff[4]; int sc[4];
  #pragma unroll
  for (int t = 0; t < 4; t++) {
    int c = w * 4 + t;
    int r = c * 8 + (lane >> 3);
    int p = lane & 7;
    int g = p ^ (r & 7);
    soff[t] = r * DMODEL + g * 8;
    sc[t] = c * 512;
  }

  f32x4 acc[4][4] = {};

  for (int k0 = 0; k0 < DMODEL; k0 += 64) {
    __syncthreads();
    #pragma unroll
    for (int t = 0; t < 4; t++) {
      async_cp16(Ag + soff[t] + k0, As + sc[t]);
      async_cp16(Bt + soff[t] + k0, Bs + sc[t]);
    }
    __syncthreads();
    #pragma unroll
    for (int kk = 0; kk < 2; kk++) {
      bf16x8 a[4], b[4];
      #pragma unroll
      for (int i = 0; i < 4; i++) {
        int row = wm * 64 + i * 16 + l16;
        int p = (kk * 4 + quad) ^ (l16 & 7);
        a[i] = as_frag(lds_ld16(As + row * 64 + p * 8));
      }
      #pragma unroll
      for (int i = 0; i < 4; i++) {
        int row = wn * 64 + i * 16 + l16;
        int p = (kk * 4 + quad) ^ (l16 & 7);
        b[i] = as_frag(lds_ld16(Bs + row * 64 + p * 8));
      }
      #pragma unroll
      for (int i = 0; i < 4; i++)
        #pragma unroll
        for (int j = 0; j < 4; j++)
          acc[i][j] = __builtin_amdgcn_mfma_f32_16x16x32_bf16(a[i], b[j], acc[i][j], 0, 0, 0);
    }
  }

  float scale = (which == 0) ? RSCALE * LOG2E : 1.0f;
  #pragma unroll
  for (int i = 0; i < 4; i++) {
    #pragma unroll
    for (int j = 0; j < 4; j++) {
      int col = wn * 64 + j * 16 + l16;       // e
      float bb = bias[col];
      #pragma unroll
      for (int r = 0; r < 4; r++) {
        int row = mt * 128 + wm * 64 + i * 16 + quad * 4 + r;
        int b_ = row >> 11, p = row & 2047;
        int bh = b_ * NHEADS + h;
        ushort val = f2bf((acc[i][j][r] + bb) * scale);
        if (which == 2) {
          Vt[((size_t)bh * DHEAD + col) * SEQ + p] = val;
        } else {
          ushort* Out = (which == 0) ? Qo : Ko;
          Out[((size_t)bh * SEQ + p) * DHEAD + col] = val;
        }
      }
    }
  }
}

// ---------------------------------------------------------------------------
// Flash attention (causal), 1 barrier/chunk: K/V double-buffered async
// staging overlaps compute; Ps is wave-private (no barrier). exp2 domain.
// Block a does qtiles {31-a, a}; 512 blocks, 2 blocks/CU.
// ---------------------------------------------------------------------------
__global__ __launch_bounds__(256, 2) void flash_attn(
    const ushort* __restrict__ Q, const ushort* __restrict__ K,
    const ushort* __restrict__ Vt, ushort* __restrict__ Z)
{
  int a  = blockIdx.x;   // 0..15
  int bh = blockIdx.y;   // 0..31
  const ushort* Qg = Q + (size_t)bh * SEQ * DHEAD;   // [2048][128]
  const ushort* Kg = K + (size_t)bh * SEQ * DHEAD;
  const ushort* Vg = Vt + (size_t)bh * DHEAD * SEQ;  // [128][2048]

  __shared__ __align__(16) ushort Ks[2][64 * 128];   // 32 KB
  __shared__ __align__(16) ushort Vs[2][128 * 64];   // 32 KB
  __shared__ __align__(16) ushort Ps[64 * 72];       // 9 KB (wave-private rows)

  int tid = threadIdx.x, lane = tid & 63, w = tid >> 6;
  int l16 = lane & 15, quad = lane >> 4;

  int kOff[4], vOff[4], cLds[4];
  #pragma unroll
  for (int t = 0; t < 4; t++) {
    int c = w * 4 + t;
    cLds[t] = c * 512;
    int rk = c * 4 + (lane >> 4);
    int pk = lane & 15;
    int gk = (pk & 8) | ((pk & 7) ^ (rk & 7));
    kOff[t] = rk * DHEAD + gk * 8;
    int ev = c * 8 + (lane >> 3);
    int pv = lane & 7;
    int gv = pv ^ (ev & 7);
    vOff[t] = ev * SEQ + gv * 8;
  }

  #pragma unroll
  for (int ph = 0; ph < 2; ph++) {
    int qt = ph ? a : (31 - a);
    int q0 = qt * 64;

    bf16x8 qf[4];
    int qrow = q0 + w * 16 + l16;
    #pragma unroll
    for (int kb = 0; kb < 4; kb++)
      qf[kb] = as_frag(*(const u32x4*)(Qg + qrow * DHEAD + kb * 32 + quad * 8));

    float m_i[4], l_i[4];
    #pragma unroll
    for (int i = 0; i < 4; i++) { m_i[i] = -1e30f; l_i[i] = 0.0f; }
    f32x4 zacc[8] = {};

    // prologue: stage chunk 0 into buffer 0
    #pragma unroll
    for (int t = 0; t < 4; t++) {
      async_cp16(Kg + kOff[t], Ks[0] + cLds[t]);
      async_cp16(Vg + vOff[t], Vs[0] + cLds[t]);
    }
    __syncthreads();   // staging 0 visible (vmcnt drained)

    for (int j = 0; j <= qt; j++) {
      int cur = j & 1;
      // issue async staging for chunk j+1 — overlaps this chunk's compute
      if (j < qt) {
        int k1 = (j + 1) * 64;
        #pragma unroll
        for (int t = 0; t < 4; t++) {
          async_cp16(Kg + k1 * DHEAD + kOff[t], Ks[cur ^ 1] + cLds[t]);
          async_cp16(Vg + k1 + vOff[t], Vs[cur ^ 1] + cLds[t]);
        }
      }
      const ushort* KsC = Ks[cur];
      const ushort* VsC = Vs[cur];

      // S = Q K^T
      f32x4 s[4] = {};
      #pragma unroll
      for (int kb = 0; kb < 4; kb++) {
        #pragma unroll
        for (int n = 0; n < 4; n++) {
          int r = n * 16 + l16;
          int ug = kb * 4 + quad;
          int p = (ug & 8) | ((ug & 7) ^ (r & 7));
          bf16x8 b = as_frag(lds_ld16(KsC + r * 128 + p * 8));
          s[n] = __builtin_amdgcn_mfma_f32_16x16x32_bf16(qf[kb], b, s[n], 0, 0, 0);
        }
      }
      // causal mask on diagonal chunk only (s already in exp2 domain)
      if (j == qt) {
        #pragma unroll
        for (int n = 0; n < 4; n++)
          #pragma unroll
          for (int i = 0; i < 4; i++) {
            int qr = 16 * w + quad * 4 + i;
            int kr = n * 16 + l16;
            if (kr > qr) s[n][i] = -1e30f;
          }
      }
      float mx[4];
      #pragma unroll
      for (int i = 0; i < 4; i++)
        mx[i] = fmaxf(fmaxf(s[0][i], s[1][i]), fmaxf(s[2][i], s[3][i]));
      #pragma unroll
      for (int off = 1; off < 16; off <<= 1)
        #pragma unroll
        for (int i = 0; i < 4; i++)
          mx[i] = fmaxf(mx[i], __shfl_xor(mx[i], off, 64));

      float alpha[4], rsum[4];
      #pragma unroll
      for (int i = 0; i < 4; i++) {
        float mn = fmaxf(m_i[i], mx[i]);
        alpha[i] = fast_exp2(m_i[i] - mn);
        m_i[i] = mn;
        rsum[i] = 0.0f;
      }
      #pragma unroll
      for (int n = 0; n < 4; n++)
        #pragma unroll
        for (int i = 0; i < 4; i++) {
          float p = fast_exp2(s[n][i] - m_i[i]);
          rsum[i] += p;
          int row = 16 * w + quad * 4 + i, col = n * 16 + l16;
          Ps[row * 72 + col] = f2bf(p);
        }
      #pragma unroll
      for (int off = 1; off < 16; off <<= 1)
        #pragma unroll
        for (int i = 0; i < 4; i++)
          rsum[i] += __shfl_xor(rsum[i], off, 64);
      #pragma unroll
      for (int i = 0; i < 4; i++) l_i[i] = l_i[i] * alpha[i] + rsum[i];
      #pragma unroll
      for (int n = 0; n < 8; n++)
        #pragma unroll
        for (int i = 0; i < 4; i++) zacc[n][i] *= alpha[i];

      // O += P V  (Ps rows are wave-private: compiler's lgkmcnt handles WAR)
      #pragma unroll
      for (int kk = 0; kk < 2; kk++) {
        bf16x8 af = as_frag(lds_ld16(Ps + (w * 16 + l16) * 72 + (kk * 4 + quad) * 8));
        #pragma unroll
        for (int n = 0; n < 8; n++) {
          int e = n * 16 + l16;
          int ug = kk * 4 + quad;
          int p = ug ^ (e & 7);
          bf16x8 b = as_frag(lds_ld16(VsC + e * 64 + p * 8));
          zacc[n] = __builtin_amdgcn_mfma_f32_16x16x32_bf16(af, b, zacc[n], 0, 0, 0);
        }
      }
      __syncthreads();   // reads of buf[cur] done; staging j+1 drained
    }

    // epilogue: Z[b*2048+pos][h*128+e] = zacc / l  (bf16)
    int b_ = bh >> 4, h = bh & 15;
    #pragma unroll
    for (int n = 0; n < 8; n++)
      #pragma unroll
      for (int i = 0; i < 4; i++) {
        int row = q0 + 16 * w + quad * 4 + i;
        int col = h * DHEAD + n * 16 + l16;
        Z[((size_t)(b_ * SEQ + row)) * DMODEL + col] = f2bf(zacc[n][i] / l_i[i]);
      }
  }
}

// ---------------------------------------------------------------------------
// Output projection (m97-style): out f32 = Z bf16 * WoT + bO
// ---------------------------------------------------------------------------
__global__ __launch_bounds__(256, 4) void gemm_out(
    const ushort* __restrict__ Zin, const ushort* __restrict__ WoT,
    const float* __restrict__ bO, float* __restrict__ out)
{
  int mt = blockIdx.x, ntile = blockIdx.y;
  __shared__ __align__(16) ushort As[128 * 64];
  __shared__ __align__(16) ushort Bs[128 * 64];
  int tid = threadIdx.x, lane = tid & 63, w = tid >> 6;
  int wm = w >> 1, wn = w & 1;
  int l16 = lane & 15, quad = lane >> 4;

  const ushort* Ag = Zin + (size_t)(mt * 128) * DMODEL;
  const ushort* Bg = WoT + (size_t)(ntile * 128) * DMODEL;

  int soff[4]; int sc[4];
  #pragma unroll
  for (int t = 0; t < 4; t++) {
    int c = w * 4 + t;
    int r = c * 8 + (lane >> 3);
    int p = lane & 7;
    int g = p ^ (r & 7);
    soff[t] = r * DMODEL + g * 8;
    sc[t] = c * 512;
  }

  f32x4 acc[4][4] = {};
  for (int k0 = 0; k0 < DMODEL; k0 += 64) {
    __syncthreads();
    #pragma unroll
    for (int t = 0; t < 4; t++) {
      async_cp16(Ag + soff[t] + k0, As + sc[t]);
      async_cp16(Bg + soff[t] + k0, Bs + sc[t]);
    }
    __syncthreads();
    #pragma unroll
    for (int kk = 0; kk < 2; kk++) {
      bf16x8 a[4], b[4];
      #pragma unroll
      for (int i = 0; i < 4; i++) {
        int row = wm * 64 + i * 16 + l16;
        int p = (kk * 4 + quad) ^ (l16 & 7);
        a[i] = as_frag(lds_ld16(As + row * 64 + p * 8));
      }
      #pragma unroll
      for (int i = 0; i < 4; i++) {
        int row = wn * 64 + i * 16 + l16;
        int p = (kk * 4 + quad) ^ (l16 & 7);
        b[i] = as_frag(lds_ld16(Bs + row * 64 + p * 8));
      }
      #pragma unroll
      for (int i = 0; i < 4; i++)
        #pragma unroll
        for (int j = 0; j < 4; j++)
          acc[i][j] = __builtin_amdgcn_mfma_f32_16x16x32_bf16(a[i], b[j], acc[i][j], 0, 0, 0);
    }
  }
  #pragma unroll
  for (int i = 0; i < 4; i++) {
    #pragma unroll
    for (int j = 0; j < 4; j++) {
      int col = ntile * 128 + wn * 64 + j * 16 + l16;
      float bb = bO[col];
      #pragma unroll
      for (int r = 0; r < 4; r++) {
        int row = mt * 128 + wm * 64 + i * 16 + quad * 4 + r;
        out[(size_t)row * DMODEL + col] = acc[i][j][r] + bb;
      }
    }
  }
}

// ---------------------------------------------------------------------------
extern "C" void kernel_launch(void* const* d_in, const int* in_sizes, int n_in,
                              void* d_out, int out_size, void* d_ws, size_t ws_size,
                              hipStream_t stream)
{
  const float* x  = (const float*)d_in[0];
  const float* Wq = (const float*)d_in[1];
  const float* Wk = (const float*)d_in[2];
  const float* Wv = (const float*)d_in[3];
  const float* Wo = (const float*)d_in[4];
  const float* bQ = (const float*)d_in[5];
  const float* bK = (const float*)d_in[6];
  const float* bV = (const float*)d_in[7];
  const float* bO = (const float*)d_in[8];
  float* out = (float*)d_out;

  ushort* ws = (ushort*)d_ws;
  const size_t WSZ = (size_t)NHEADS * DHEAD * DMODEL;       // 4,194,304
  const size_t QSZ = (size_t)BATCH * NHEADS * SEQ * DHEAD;  // 8,388,608
  ushort* xb  = ws;
  ushort* WqT = xb + (size_t)MROWS * DMODEL;
  ushort* WkT = WqT + WSZ;
  ushort* WvT = WkT + WSZ;
  ushort* WoT = WvT + WSZ;
  ushort* Qb  = WoT + (size_t)DMODEL * DMODEL;
  ushort* Kb  = Qb + QSZ;
  ushort* VtB = Kb + QSZ;
  ushort* Zb  = VtB + QSZ;

  dim3 tb(256);
  prep<<<dim3(24576), tb, 0, stream>>>(x, Wq, Wk, Wv, Wo,
                                       xb, WqT, WkT, WvT, WoT);

  gemm_qkv<<<dim3(32, 16, 3), tb, 0, stream>>>(xb, WqT, WkT, WvT, bQ, bK, bV,
                                               Qb, Kb, VtB);

  flash_attn<<<dim3(16, 32), tb, 0, stream>>>(Qb, Kb, VtB, Zb);

  gemm_out<<<dim3(32, 16), tb, 0, stream>>>(Zb, WoT, bO, out);
}